// Round 3
// baseline (699.545 us; speedup 1.0000x reference)
//
#include <hip/hip_runtime.h>
#include <math.h>

typedef unsigned short u16;
typedef unsigned int   u32;

static constexpr int B_=4, C_=256, K_=5, D_=256, N_=4096, IT_=4;
static constexpr float EPS_=1e-5f;

__device__ __forceinline__ float bf2f(u16 u){ u32 x=((u32)u)<<16; float f; __builtin_memcpy(&f,&x,4); return f; }
__device__ __forceinline__ u16 f2bf(float f){ u32 x; __builtin_memcpy(&x,&f,4); u32 r=x+0x7fffu+((x>>16)&1u); return (u16)(r>>16); }
// flag==1: inputs/outputs are float32; flag==0: bf16
__device__ __forceinline__ float ldin(const void* p, size_t i, int f){
  return f ? ((const float*)p)[i] : bf2f(((const u16*)p)[i]);
}
__device__ __forceinline__ void stout(void* p, size_t i, float v, int f){
  if (f) ((float*)p)[i]=v; else ((u16*)p)[i]=f2bf(v);
}

// ---- block (256-thread, 4-wave) reductions ----
__device__ __forceinline__ void breduce4(float&a,float&b,float&c,float&d,float* red){
  #pragma unroll
  for(int o=32;o>0;o>>=1){
    a+=__shfl_down(a,o,64); b+=__shfl_down(b,o,64);
    c+=__shfl_down(c,o,64); d+=__shfl_down(d,o,64);
  }
  int w=threadIdx.x>>6;
  __syncthreads();
  if((threadIdx.x&63)==0){ red[w]=a; red[4+w]=b; red[8+w]=c; red[12+w]=d; }
  __syncthreads();
  a=red[0]+red[1]+red[2]+red[3];
  b=red[4]+red[5]+red[6]+red[7];
  c=red[8]+red[9]+red[10]+red[11];
  d=red[12]+red[13]+red[14]+red[15];
}
__device__ __forceinline__ float breduce_max(float v, float* red){
  #pragma unroll
  for(int o=32;o>0;o>>=1) v=fmaxf(v,__shfl_down(v,o,64));
  int w=threadIdx.x>>6;
  __syncthreads();
  if((threadIdx.x&63)==0) red[w]=v;
  __syncthreads();
  return fmaxf(fmaxf(red[0],red[1]),fmaxf(red[2],red[3]));
}
__device__ __forceinline__ float breduce_sum(float v, float* red){
  #pragma unroll
  for(int o=32;o>0;o>>=1) v+=__shfl_down(v,o,64);
  int w=threadIdx.x>>6;
  __syncthreads();
  if((threadIdx.x&63)==0) red[w]=v;
  __syncthreads();
  return red[0]+red[1]+red[2]+red[3];
}
__device__ __forceinline__ void breduce_minmax(float& mn, float& mx, float* red){
  #pragma unroll
  for(int o=32;o>0;o>>=1){ mn=fminf(mn,__shfl_down(mn,o,64)); mx=fmaxf(mx,__shfl_down(mx,o,64)); }
  int w=threadIdx.x>>6;
  __syncthreads();
  if((threadIdx.x&63)==0){ red[w]=mn; red[4+w]=mx; }
  __syncthreads();
  mn=fminf(fminf(red[0],red[1]),fminf(red[2],red[3]));
  mx=fmaxf(fmaxf(red[4],red[5]),fmaxf(red[6],red[7]));
}

// ---- dtype probe: f32 data read as bf16-low-halves yields wild exponents ----
__global__ void probe_kernel(const void* feat, int* flag){
  __shared__ float red[16];
  const u32* p=(const u32*)feat;
  int t=threadIdx.x; int bad=0;
  for(int s=0;s<8;++s){
    u32 wd=p[t+s*256];
    float lo=bf2f((u16)(wd&0xffffu));
    if(!(fabsf(lo)<1e6f)) bad++;
  }
  float bb=(float)bad, z1=0,z2=0,z3=0;
  breduce4(bb,z1,z2,z3,red);
  if(t==0) *flag = (bb>=16.f)?1:0;
}

// ---- prep: weight transposes (-> f32), slot init, ge basis vectors ----
__global__ void prep1_kernel(const int* flag,
    const void* kW, const void* vW, const void* mW, const void* qW, const void* rW,
    const void* Wih, const void* Whh, const void* mu, const void* lsig, const void* noise,
    const void* gW, const void* gb_, const void* mg,
    float* WkT, float* WvT, float* WgT, float* WqT, float* WrT,
    float* WihT, float* WhhT, float* slot, float* gvec)
{
  int f=*flag;
  int e=blockIdx.x*256+threadIdx.x;
  if(e<65536){ int r=e>>8,c=e&255; WkT[c*256+r]=ldin(kW,e,f); return;} e-=65536;
  if(e<65536){ int r=e>>8,c=e&255; WvT[c*256+r]=ldin(vW,e,f); return;} e-=65536;
  if(e<65536){ int r=e>>8,c=e&255; WgT[c*256+r]=ldin(mg,c,f)*ldin(mW,e,f); return;} e-=65536;
  if(e<65536){ int r=e>>8,c=e&255; WqT[c*256+r]=ldin(qW,e,f); return;} e-=65536;
  if(e<65536){ int r=e>>8,c=e&255; WrT[c*256+r]=ldin(rW,e,f); return;} e-=65536;
  if(e<196608){ int r=e>>8,c=e&255; WihT[c*768+r]=ldin(Wih,e,f); return;} e-=196608;
  if(e<196608){ int r=e>>8,c=e&255; WhhT[c*768+r]=ldin(Whh,e,f); return;} e-=196608;
  if(e<5120){ int d=e&255; slot[e]=ldin(mu,d,f)+expf(ldin(lsig,d,f))*ldin(noise,e,f); return;} e-=5120;
  if(e<768){
    int c=e&255, sel=e>>8;
    float v;
    if(sel==0)      v=ldin(gW,c*4+0,f)-ldin(gW,c*4+2,f);   // gA
    else if(sel==1) v=ldin(gW,c*4+1,f)-ldin(gW,c*4+3,f);   // gB
    else            v=ldin(gb_,c,f);                        // gb
    gvec[e]=v;
  }
}

// ---- U vectors (shared mlp for k and v) + quadratic scalars ----
__global__ void uq_kernel(const int* flag, const float* WgT, const void* mW, const void* mb_, const void* mbias,
                          const float* gvec, float* Uvec, float* Qs)
{
  __shared__ float ga[256], gB[256], gc[256]; __shared__ float red[16];
  int t=threadIdx.x; int f=*flag;
  ga[t]=gvec[t]; gB[t]=gvec[256+t]; gc[t]=gvec[512+t];
  __syncthreads();
  float u1=0,u2=0,u3=0,gw=0,bw=0;
  for(int c=0;c<256;++c){
    float wg=WgT[c*256+t];                 // g_c * W[t][c]
    u1+=ga[c]*wg; u2+=gB[c]*wg; u3+=gc[c]*wg; gw+=wg;
    bw+=ldin(mb_,c,f)*ldin(mW,(size_t)t*256+c,f);
  }
  Uvec[t]=u1; Uvec[256+t]=u2; Uvec[512+t]=u3; Uvec[768+t]=gw;
  Uvec[1024+t]=bw+ldin(mbias,t,f);
  float a=ga[t], b=gB[t], cc=gc[t];
  float s0=a*a,s1=b*b,s2=cc*cc,s3=a*b; breduce4(s0,s1,s2,s3,red);
  float s4=a*cc,s5=b*cc,s6=a,s7=b;     breduce4(s4,s5,s6,s7,red);
  float s8=cc,z1=0,z2=0,z3=0;          breduce4(s8,z1,z2,z3,red);
  if(t==0){
    Qs[0]=s0; Qs[1]=s1; Qs[2]=s2; Qs[3]=s3; Qs[4]=s4; Qs[5]=s5;
    Qs[6]=s6*(1.f/256.f); Qs[7]=s7*(1.f/256.f); Qs[8]=s8*(1.f/256.f);
  }
}

// ---- fg_pos ----
__global__ void fgpos_kernel(const int* flag, const void* mask, float* fg, void* out)
{
  __shared__ float red[16];
  int k=blockIdx.x, t=threadIdx.x, f=*flag;
  float sx=0,sy=0,sm=0;
  for(int s=0;s<16;++s){
    int p=t+s*256;
    float m=ldin(mask,(size_t)k*N_+p,f);
    int i=p>>6, j=p&63;
    float x=(2*j+1)*(1.0f/64.0f)-1.0f;
    float y=(2*i+1)*(1.0f/64.0f)-1.0f;
    sx+=x*m; sy+=y*m; sm+=m;
  }
  float d=0;
  breduce4(sx,sy,sm,d,red);
  if(t==0){
    float inv=1.0f/(sm+1e-5f);
    float fx=sx*inv, fy=sy*inv;
    fg[k*2]=fx; fg[k*2+1]=fy;
    for(int b=0;b<B_;++b){
      stout(out, 5120+(b*K_+k)*2+0, fx, f);
      stout(out, 5120+(b*K_+k)*2+1, fy, f);
    }
  }
}

// ---- base: LN(feat) -> kbase/vbase (LDS) -> per-row scalars + Pk/Pv GEMMs ----
__global__ void __launch_bounds__(256) base_kernel(const int* flag, const void* feat, const void* ng, const void* nb,
    const float* WkT, const float* WvT, const float* WgT, const float* gvec,
    float* scal, float* Pk, float* Pv)
{
  __shared__ float fn[8][256];
  __shared__ float kb[8][256];
  __shared__ float vb[8][256];
  __shared__ float red[16];
  int t=threadIdx.x, f=*flag;
  int row0=blockIdx.x*8;                 // row = b*N+n
  float g=ldin(ng,t,f), bb=ldin(nb,t,f);
  for(int r=0;r<8;++r){
    float x=ldin(feat,(size_t)(row0+r)*256+t,f);
    float s=x,s2=x*x,d0=0,d1=0; breduce4(s,s2,d0,d1,red);
    float m=s*(1.f/256.f), var=s2*(1.f/256.f)-m*m;
    fn[r][t]=(x-m)*rsqrtf(var+EPS_)*g+bb;
  }
  __syncthreads();
  int w=t>>6, l=t&63, d0=l*4;
  { // kbase/vbase: wave w -> rows 2w, 2w+1
    float a0[4]={0,0,0,0},a1[4]={0,0,0,0},b0[4]={0,0,0,0},b1[4]={0,0,0,0};
    for(int c=0;c<256;++c){
      float4 wk=*(const float4*)(WkT+c*256+d0);
      float4 wv=*(const float4*)(WvT+c*256+d0);
      float f0=fn[2*w][c], f1=fn[2*w+1][c];
      a0[0]+=f0*wk.x; a0[1]+=f0*wk.y; a0[2]+=f0*wk.z; a0[3]+=f0*wk.w;
      a1[0]+=f1*wk.x; a1[1]+=f1*wk.y; a1[2]+=f1*wk.z; a1[3]+=f1*wk.w;
      b0[0]+=f0*wv.x; b0[1]+=f0*wv.y; b0[2]+=f0*wv.z; b0[3]+=f0*wv.w;
      b1[0]+=f1*wv.x; b1[1]+=f1*wv.y; b1[2]+=f1*wv.z; b1[3]+=f1*wv.w;
    }
    kb[2*w][d0]=a0[0]; kb[2*w][d0+1]=a0[1]; kb[2*w][d0+2]=a0[2]; kb[2*w][d0+3]=a0[3];
    kb[2*w+1][d0]=a1[0]; kb[2*w+1][d0+1]=a1[1]; kb[2*w+1][d0+2]=a1[2]; kb[2*w+1][d0+3]=a1[3];
    vb[2*w][d0]=b0[0]; vb[2*w][d0+1]=b0[1]; vb[2*w][d0+2]=b0[2]; vb[2*w][d0+3]=b0[3];
    vb[2*w+1][d0]=b1[0]; vb[2*w+1][d0+1]=b1[1]; vb[2*w+1][d0+2]=b1[2]; vb[2*w+1][d0+3]=b1[3];
  }
  __syncthreads();
  // per-row scalars: {Σkb, Σkb², Σkb·gA, Σkb·gB, Σkb·gb} and same for vb
  float gA=gvec[t], gBv=gvec[256+t], gC=gvec[512+t];
  for(int r=0;r<8;++r){
    float xk=kb[r][t], xv=vb[r][t];
    float s0=xk, s1=xk*xk, s2=xk*gA, s3=xk*gBv; breduce4(s0,s1,s2,s3,red);
    float s4=xk*gC, s5=xv, s6=xv*xv, s7=xv*gA;  breduce4(s4,s5,s6,s7,red);
    float s8=xv*gBv, s9=xv*gC, z0=0, z1=0;      breduce4(s8,s9,z0,z1,red);
    if(t==0){
      float* sc=scal+(size_t)(row0+r)*10;
      sc[0]=s0; sc[1]=s1; sc[2]=s2; sc[3]=s3; sc[4]=s4;
      sc[5]=s5; sc[6]=s6; sc[7]=s7; sc[8]=s8; sc[9]=s9;
    }
  }
  // Pk/Pv = (kbase ⊙ g) @ W.T via WgT
  {
    float a0[4]={0,0,0,0},a1[4]={0,0,0,0},b0[4]={0,0,0,0},b1[4]={0,0,0,0};
    for(int c=0;c<256;++c){
      float4 wg=*(const float4*)(WgT+c*256+d0);
      float k0=kb[2*w][c], k1=kb[2*w+1][c], v0=vb[2*w][c], v1=vb[2*w+1][c];
      a0[0]+=k0*wg.x; a0[1]+=k0*wg.y; a0[2]+=k0*wg.z; a0[3]+=k0*wg.w;
      a1[0]+=k1*wg.x; a1[1]+=k1*wg.y; a1[2]+=k1*wg.z; a1[3]+=k1*wg.w;
      b0[0]+=v0*wg.x; b0[1]+=v0*wg.y; b0[2]+=v0*wg.z; b0[3]+=v0*wg.w;
      b1[0]+=v1*wg.x; b1[1]+=v1*wg.y; b1[2]+=v1*wg.z; b1[3]+=v1*wg.w;
    }
    *(float4*)(Pk+(size_t)(row0+2*w)*256+d0)  =make_float4(a0[0],a0[1],a0[2],a0[3]);
    *(float4*)(Pk+(size_t)(row0+2*w+1)*256+d0)=make_float4(a1[0],a1[1],a1[2],a1[3]);
    *(float4*)(Pv+(size_t)(row0+2*w)*256+d0)  =make_float4(b0[0],b0[1],b0[2],b0[3]);
    *(float4*)(Pv+(size_t)(row0+2*w+1)*256+d0)=make_float4(b1[0],b1[1],b1[2],b1[3]);
  }
}

// ---- per-(b,k,n) LN mean / inv-sigma for k and v paths ----
__global__ void invm_kernel(const float* fg, const float* Qs, const float* scal,
                            float* invK, float* mK, float* invV, float* mV)
{
  int g=blockIdx.x*256+threadIdx.x;      // 81920
  int n=g&4095, bk=g>>12; int k=bk%K_, b=bk/K_;
  int i=n>>6, j=n&63;
  float rx=(2*j+1)*(1.f/64.f)-1.f-fg[k*2];
  float ry=(2*i+1)*(1.f/64.f)-1.f-fg[k*2+1];
  const float* sc=scal+(size_t)(b*N_+n)*10;
  float QA=Qs[0],QB=Qs[1],QC=Qs[2],QAB=Qs[3],QAC=Qs[4],QBC=Qs[5],mA=Qs[6],mB=Qs[7],mC=Qs[8];
  float qge=rx*rx*QA+ry*ry*QB+QC+2.f*(rx*ry*QAB+rx*QAC+ry*QBC);
  float mk=sc[0]*(1.f/256.f)+rx*mA+ry*mB+mC;
  float sxk=sc[1]+2.f*(rx*sc[2]+ry*sc[3]+sc[4])+qge;
  float vk=sxk*(1.f/256.f)-mk*mk;
  invK[g]=rsqrtf(vk+EPS_); mK[g]=mk;
  float mv=sc[5]*(1.f/256.f)+rx*mA+ry*mB+mC;
  float sxv=sc[6]+2.f*(rx*sc[7]+ry*sc[8]+sc[9])+qge;
  float vv_=sxv*(1.f/256.f)-mv*mv;
  invV[g]=rsqrtf(vv_+EPS_); mV[g]=mv;
}

// ---- q = LN(slot) @ q_W.T ; q-side scalars; zero accumulators ----
__global__ void q_kernel(const int* flag, const float* slot, const void* qg, const void* qb_,
                         const float* WqT, const float* Uvec,
                         float* qbuf, float* updbuf, float* qsc, float* ssc)
{
  __shared__ float Lq[256]; __shared__ float qsh[256]; __shared__ float red[16];
  int bk=blockIdx.x, t=threadIdx.x, f=*flag;
  float x=slot[bk*256+t];
  float s=x,s2=x*x,d0=0,d1=0; breduce4(s,s2,d0,d1,red);
  float m=s*(1.f/256.f), v=s2*(1.f/256.f)-m*m;
  Lq[t]=(x-m)*rsqrtf(v+EPS_)*ldin(qg,t,f)+ldin(qb_,t,f);
  __syncthreads();
  float acc=0;
  for(int c=0;c<256;++c) acc+=Lq[c]*WqT[c*256+t];
  qbuf[bk*256+t]=acc; qsh[t]=acc; updbuf[bk*256+t]=0.f;
  __syncthreads();
  float q=qsh[t];
  float s0=q*Uvec[t], s1=q*Uvec[256+t], s2b=q*Uvec[512+t], s3=q*Uvec[768+t];
  breduce4(s0,s1,s2b,s3,red);
  float s4=q*Uvec[1024+t], z1=0,z2=0,z3=0;
  breduce4(s4,z1,z2,z3,red);
  if(t<4) ssc[bk*4+t]=0.f;
  if(t==0){ qsc[bk*8+0]=s0; qsc[bk*8+1]=s1; qsc[bk*8+2]=s2b; qsc[bk*8+3]=s3; qsc[bk*8+4]=s4; }
}

// ---- logits[b,k,n] = scale*(inv*(q·P + rx qU1 + ry qU2 + qU3 - m qGw) + qc5), masked ----
__global__ void __launch_bounds__(256) logits_kernel(const int* flag, const float* qbuf, const float* Pk,
    const float* invK, const float* mK, const float* qsc, const float* fg, const void* mask, float* logits)
{
  __shared__ float qs[256];
  int t=threadIdx.x, f=*flag;
  int gid=blockIdx.x*256+t;
  int bk=blockIdx.x>>4; int k=bk%K_, b=bk/K_;
  qs[t]=qbuf[bk*256+t];
  __syncthreads();
  int n=gid&4095; int i=n>>6, j=n&63;
  float rx=(2*j+1)*(1.f/64.f)-1.f-fg[k*2];
  float ry=(2*i+1)*(1.f/64.f)-1.f-fg[k*2+1];
  const float4* pr=(const float4*)(Pk+(size_t)(b*N_+n)*256);
  const float4* q4=(const float4*)qs;
  float acc=0;
  #pragma unroll 8
  for(int c=0;c<64;++c){
    float4 p=pr[c], qq=q4[c];
    acc+=p.x*qq.x+p.y*qq.y+p.z*qq.z+p.w*qq.w;
  }
  float lg=invK[gid]*(acc+rx*qsc[bk*8+0]+ry*qsc[bk*8+1]+qsc[bk*8+2]-mK[gid]*qsc[bk*8+3])+qsc[bk*8+4];
  float mval=ldin(mask,(size_t)k*N_+n,f);
  logits[gid]=(mval==0.f)? -1e9f : lg*0.0625f;
}

__global__ void softmax_kernel(const float* logits, float* attn)
{
  __shared__ float red[16];
  int bk=blockIdx.x, t=threadIdx.x;
  float l[16]; float mx=-1e30f;
  for(int s=0;s<16;++s){ l[s]=logits[bk*N_+t+s*256]; mx=fmaxf(mx,l[s]); }
  mx=breduce_max(mx,red);
  float sum=0;
  for(int s=0;s<16;++s){ l[s]=expf(l[s]-mx); sum+=l[s]; }
  sum=breduce_sum(sum,red);
  float inv=1.0f/sum;
  for(int s=0;s<16;++s) attn[bk*N_+t+s*256]=l[s]*inv;
}

// ---- upd partials: Σ w·Pv (vector) + {Σw·rx, Σw·ry, Σw, Σw·mV} (scalars), w = attn*invV ----
__global__ void __launch_bounds__(256) upd_kernel(const float* attn, const float* invV, const float* mV,
    const float* Pv, const float* fg, float* updbuf, float* ssc)
{
  __shared__ float part[4][256]; __shared__ float sred[4][4];
  int t=threadIdx.x, w=t>>6, l=t&63;
  int blk=blockIdx.x; int bk=blk>>3, ch=blk&7; int k=bk%K_, b=bk/K_;
  int n0=ch*512+w*128; int d0=l*4;
  float fgx=fg[k*2], fgy=fg[k*2+1];
  float a0=0,a1=0,a2=0,a3=0, sw=0,swx=0,swy=0,swm=0;
  for(int s=0;s<128;++s){
    int n=n0+s;
    float wgt=attn[(size_t)bk*N_+n]*invV[(size_t)bk*N_+n];
    float4 p=*(const float4*)(Pv+(size_t)(b*N_+n)*256+d0);
    a0+=wgt*p.x; a1+=wgt*p.y; a2+=wgt*p.z; a3+=wgt*p.w;
    int i=n>>6, j=n&63;
    float rx=(2*j+1)*(1.f/64.f)-1.f-fgx;
    float ry=(2*i+1)*(1.f/64.f)-1.f-fgy;
    sw+=wgt; swx+=wgt*rx; swy+=wgt*ry; swm+=wgt*mV[(size_t)bk*N_+n];
  }
  part[w][d0]=a0; part[w][d0+1]=a1; part[w][d0+2]=a2; part[w][d0+3]=a3;
  if(l==0){ sred[w][0]=swx; sred[w][1]=swy; sred[w][2]=sw; sred[w][3]=swm; }
  __syncthreads();
  float v=part[0][t]+part[1][t]+part[2][t]+part[3][t];
  atomicAdd(updbuf+bk*256+t, v);
  if(t<4){ float sv=sred[0][t]+sred[1][t]+sred[2][t]+sred[3][t]; atomicAdd(ssc+bk*4+t, sv); }
}

// ---- GRU + residual MLP slot update; composes upd from partials first ----
__global__ void __launch_bounds__(256) gru_kernel(const int* flag, float* slot, const float* updbuf,
    const float* Uvec, const float* ssc,
    const float* WihT, const float* WhhT, const void* bih, const void* bhh,
    const void* rg, const void* rb_, const float* WrT, const void* rbias)
{
  __shared__ float u[256], h[256], Ln[256], red[16];
  int bk=blockIdx.x, t=threadIdx.x, f=*flag;
  float c1=ssc[bk*4+0], c2=ssc[bk*4+1], c3=ssc[bk*4+2], c4=ssc[bk*4+3];
  u[t]=updbuf[bk*256+t]+c1*Uvec[t]+c2*Uvec[256+t]+c3*Uvec[512+t]-c4*Uvec[768+t]+Uvec[1024+t];
  h[t]=slot[bk*256+t];
  __syncthreads();
  float gi0=ldin(bih,t,f), gi1=ldin(bih,256+t,f), gi2=ldin(bih,512+t,f);
  float gh0=ldin(bhh,t,f), gh1=ldin(bhh,256+t,f), gh2=ldin(bhh,512+t,f);
  #pragma unroll 4
  for(int c=0;c<256;++c){
    float uc=u[c], hc=h[c];
    const float* wi=WihT+c*768+t;
    const float* wh=WhhT+c*768+t;
    gi0+=uc*wi[0]; gi1+=uc*wi[256]; gi2+=uc*wi[512];
    gh0+=hc*wh[0]; gh1+=hc*wh[256]; gh2+=hc*wh[512];
  }
  float r=1.f/(1.f+expf(-(gi0+gh0)));
  float z=1.f/(1.f+expf(-(gi1+gh1)));
  float nn=tanhf(gi2+r*gh2);
  float hn=(1.f-z)*nn+z*h[t];
  float s=hn, sq=hn*hn, dd0=0, dd1=0;
  breduce4(s,sq,dd0,dd1,red);
  float m=s*(1.f/256.f), var=sq*(1.f/256.f)-m*m;
  Ln[t]=(hn-m)*rsqrtf(var+EPS_)*ldin(rg,t,f)+ldin(rb_,t,f);
  __syncthreads();
  float acc=ldin(rbias,t,f)+h[t];
  for(int c=0;c<256;++c) acc+=Ln[c]*WrT[c*256+t];
  slot[bk*256+t]=acc;
}

// ---- outputs ----
__global__ void slotout_kernel(const int* flag, const float* slot, void* out)
{
  int e=blockIdx.x*256+threadIdx.x;
  stout(out, e, slot[e], *flag);
}
__global__ void vis_kernel(const int* flag, const float* attn, void* out)
{
  __shared__ float red[16];
  int bk=blockIdx.x, t=threadIdx.x, f=*flag;
  float a[16]; float mn=1e30f, mx=-1e30f;
  for(int s=0;s<16;++s){ a[s]=attn[bk*N_+t+s*256]; mn=fminf(mn,a[s]); mx=fmaxf(mx,a[s]); }
  breduce_minmax(mn,mx,red);
  float inv=1.0f/(mx-mn+1e-5f);
  for(int s=0;s<16;++s) stout(out, 5160+(size_t)bk*N_+t+s*256, (a[s]-mn)*inv, f);
}

extern "C" void kernel_launch(void* const* d_in, const int* in_sizes, int n_in,
                              void* d_out, int out_size, void* d_ws, size_t ws_size,
                              hipStream_t stream)
{
  const void* feat =d_in[0];  const void* mask =d_in[1];  const void* noise=d_in[2];
  const void* mu   =d_in[3];  const void* lsig =d_in[4];  const void* ng   =d_in[5];
  const void* nb   =d_in[6];  const void* gW   =d_in[7];  const void* gb_  =d_in[8];
  const void* kW   =d_in[9];  const void* vW   =d_in[10]; const void* mg   =d_in[11];
  const void* mb_  =d_in[12]; const void* mW   =d_in[13]; const void* mbias=d_in[14];
  const void* qg   =d_in[15]; const void* qb_  =d_in[16]; const void* qW   =d_in[17];
  const void* Wih  =d_in[18]; const void* Whh  =d_in[19]; const void* bih  =d_in[20];
  const void* bhh  =d_in[21]; const void* rg   =d_in[22]; const void* rb_  =d_in[23];
  const void* rW   =d_in[24]; const void* rbias=d_in[25];

  char* p=(char*)d_ws;
  auto alloc=[&](size_t bytes)->char*{ char* r=p; p+=(bytes+255)&~(size_t)255; return r; };
  int*   flag  =(int*)  alloc(256);
  float* fg    =(float*)alloc(64);
  float* slot  =(float*)alloc(5120*4);
  float* qbuf  =(float*)alloc(5120*4);
  float* updbuf=(float*)alloc(5120*4);
  float* qsc   =(float*)alloc(160*4);
  float* ssc   =(float*)alloc(80*4);
  float* logits=(float*)alloc((size_t)81920*4);
  float* attn  =(float*)alloc((size_t)81920*4);
  float* WkT   =(float*)alloc((size_t)65536*4);
  float* WvT   =(float*)alloc((size_t)65536*4);
  float* WgT   =(float*)alloc((size_t)65536*4);
  float* WqT   =(float*)alloc((size_t)65536*4);
  float* WrT   =(float*)alloc((size_t)65536*4);
  float* WihT  =(float*)alloc((size_t)196608*4);
  float* WhhT  =(float*)alloc((size_t)196608*4);
  float* gvec  =(float*)alloc(768*4);
  float* Uvec  =(float*)alloc(1280*4);
  float* Qs    =(float*)alloc(64);
  float* scal  =(float*)alloc((size_t)163840*4);
  float* invK  =(float*)alloc((size_t)81920*4);
  float* mK    =(float*)alloc((size_t)81920*4);
  float* invV  =(float*)alloc((size_t)81920*4);
  float* mV    =(float*)alloc((size_t)81920*4);
  float* Pk    =(float*)alloc((size_t)16384*256*4);
  float* Pv    =(float*)alloc((size_t)16384*256*4);

  probe_kernel<<<1,256,0,stream>>>(feat, flag);
  prep1_kernel<<<2839,256,0,stream>>>(flag,kW,vW,mW,qW,rW,Wih,Whh,mu,lsig,noise,gW,gb_,mg,
                                      WkT,WvT,WgT,WqT,WrT,WihT,WhhT,slot,gvec);
  uq_kernel<<<1,256,0,stream>>>(flag,WgT,mW,mb_,mbias,gvec,Uvec,Qs);
  fgpos_kernel<<<K_,256,0,stream>>>(flag,mask,fg,d_out);
  base_kernel<<<(B_*N_)/8,256,0,stream>>>(flag,feat,ng,nb,WkT,WvT,WgT,gvec,scal,Pk,Pv);
  invm_kernel<<<320,256,0,stream>>>(fg,Qs,scal,invK,mK,invV,mV);
  for(int it=0; it<IT_; ++it){
    q_kernel<<<B_*K_,256,0,stream>>>(flag,slot,qg,qb_,WqT,Uvec,qbuf,updbuf,qsc,ssc);
    logits_kernel<<<(B_*K_*N_)/256,256,0,stream>>>(flag,qbuf,Pk,invK,mK,qsc,fg,mask,logits);
    softmax_kernel<<<B_*K_,256,0,stream>>>(logits,attn);
    upd_kernel<<<B_*K_*8,256,0,stream>>>(attn,invV,mV,Pv,fg,updbuf,ssc);
    gru_kernel<<<B_*K_,256,0,stream>>>(flag,slot,updbuf,Uvec,ssc,WihT,WhhT,bih,bhh,rg,rb_,WrT,rbias);
  }
  slotout_kernel<<<B_*K_,256,0,stream>>>(flag,slot,d_out);
  vis_kernel<<<B_*K_,256,0,stream>>>(flag,attn,d_out);
}

// Round 4
// 669.740 us; speedup vs baseline: 1.0445x; 1.0445x over previous
//
#include <hip/hip_runtime.h>
#include <math.h>

typedef unsigned short u16;
typedef unsigned int   u32;

static constexpr int B_=4, C_=256, K_=5, D_=256, N_=4096, IT_=4;
static constexpr float EPS_=1e-5f;

__device__ __forceinline__ float bf2f(u16 u){ u32 x=((u32)u)<<16; float f; __builtin_memcpy(&f,&x,4); return f; }
__device__ __forceinline__ u16 f2bf(float f){ u32 x; __builtin_memcpy(&x,&f,4); u32 r=x+0x7fffu+((x>>16)&1u); return (u16)(r>>16); }
// flag==1: inputs/outputs are float32; flag==0: bf16
__device__ __forceinline__ float ldin(const void* p, size_t i, int f){
  return f ? ((const float*)p)[i] : bf2f(((const u16*)p)[i]);
}
__device__ __forceinline__ void stout(void* p, size_t i, float v, int f){
  if (f) ((float*)p)[i]=v; else ((u16*)p)[i]=f2bf(v);
}

// ---- block (256-thread, 4-wave) reductions ----
__device__ __forceinline__ void breduce4(float&a,float&b,float&c,float&d,float* red){
  #pragma unroll
  for(int o=32;o>0;o>>=1){
    a+=__shfl_down(a,o,64); b+=__shfl_down(b,o,64);
    c+=__shfl_down(c,o,64); d+=__shfl_down(d,o,64);
  }
  int w=threadIdx.x>>6;
  __syncthreads();
  if((threadIdx.x&63)==0){ red[w]=a; red[4+w]=b; red[8+w]=c; red[12+w]=d; }
  __syncthreads();
  a=red[0]+red[1]+red[2]+red[3];
  b=red[4]+red[5]+red[6]+red[7];
  c=red[8]+red[9]+red[10]+red[11];
  d=red[12]+red[13]+red[14]+red[15];
}
__device__ __forceinline__ float breduce_max(float v, float* red){
  #pragma unroll
  for(int o=32;o>0;o>>=1) v=fmaxf(v,__shfl_down(v,o,64));
  int w=threadIdx.x>>6;
  __syncthreads();
  if((threadIdx.x&63)==0) red[w]=v;
  __syncthreads();
  return fmaxf(fmaxf(red[0],red[1]),fmaxf(red[2],red[3]));
}
__device__ __forceinline__ float breduce_sum(float v, float* red){
  #pragma unroll
  for(int o=32;o>0;o>>=1) v+=__shfl_down(v,o,64);
  int w=threadIdx.x>>6;
  __syncthreads();
  if((threadIdx.x&63)==0) red[w]=v;
  __syncthreads();
  return red[0]+red[1]+red[2]+red[3];
}
__device__ __forceinline__ void breduce_minmax(float& mn, float& mx, float* red){
  #pragma unroll
  for(int o=32;o>0;o>>=1){ mn=fminf(mn,__shfl_down(mn,o,64)); mx=fmaxf(mx,__shfl_down(mx,o,64)); }
  int w=threadIdx.x>>6;
  __syncthreads();
  if((threadIdx.x&63)==0){ red[w]=mn; red[4+w]=mx; }
  __syncthreads();
  mn=fminf(fminf(red[0],red[1]),fminf(red[2],red[3]));
  mx=fmaxf(fmaxf(red[4],red[5]),fmaxf(red[6],red[7]));
}

// ---- dtype probe ----
__global__ void probe_kernel(const void* feat, int* flag){
  __shared__ float red[16];
  const u32* p=(const u32*)feat;
  int t=threadIdx.x; int bad=0;
  for(int s=0;s<8;++s){
    u32 wd=p[t+s*256];
    float lo=bf2f((u16)(wd&0xffffu));
    if(!(fabsf(lo)<1e6f)) bad++;
  }
  float bb=(float)bad, z1=0,z2=0,z3=0;
  breduce4(bb,z1,z2,z3,red);
  if(t==0) *flag = (bb>=16.f)?1:0;
}

// ---- prep: weight transposes (-> f32), slot init, ge basis vectors ----
__global__ void prep1_kernel(const int* flag,
    const void* kW, const void* vW, const void* mW, const void* qW, const void* rW,
    const void* Wih, const void* Whh, const void* mu, const void* lsig, const void* noise,
    const void* gW, const void* gb_, const void* mg,
    float* WkT, float* WvT, float* WgT, float* WqT, float* WrT,
    float* WihT, float* WhhT, float* slot, float* gvec)
{
  int f=*flag;
  int e=blockIdx.x*256+threadIdx.x;
  if(e<65536){ int r=e>>8,c=e&255; WkT[c*256+r]=ldin(kW,e,f); return;} e-=65536;
  if(e<65536){ int r=e>>8,c=e&255; WvT[c*256+r]=ldin(vW,e,f); return;} e-=65536;
  if(e<65536){ int r=e>>8,c=e&255; WgT[c*256+r]=ldin(mg,c,f)*ldin(mW,e,f); return;} e-=65536;
  if(e<65536){ int r=e>>8,c=e&255; WqT[c*256+r]=ldin(qW,e,f); return;} e-=65536;
  if(e<65536){ int r=e>>8,c=e&255; WrT[c*256+r]=ldin(rW,e,f); return;} e-=65536;
  if(e<196608){ int r=e>>8,c=e&255; WihT[c*768+r]=ldin(Wih,e,f); return;} e-=196608;
  if(e<196608){ int r=e>>8,c=e&255; WhhT[c*768+r]=ldin(Whh,e,f); return;} e-=196608;
  if(e<5120){ int d=e&255; slot[e]=ldin(mu,d,f)+expf(ldin(lsig,d,f))*ldin(noise,e,f); return;} e-=5120;
  if(e<768){
    int c=e&255, sel=e>>8;
    float v;
    if(sel==0)      v=ldin(gW,c*4+0,f)-ldin(gW,c*4+2,f);   // gA
    else if(sel==1) v=ldin(gW,c*4+1,f)-ldin(gW,c*4+3,f);   // gB
    else            v=ldin(gb_,c,f);                        // gb
    gvec[e]=v;
  }
}

// ---- U vectors + quadratic scalars ----
__global__ void uq_kernel(const int* flag, const float* WgT, const void* mW, const void* mb_, const void* mbias,
                          const float* gvec, float* Uvec, float* Qs)
{
  __shared__ float ga[256], gB[256], gc[256]; __shared__ float red[16];
  int t=threadIdx.x; int f=*flag;
  ga[t]=gvec[t]; gB[t]=gvec[256+t]; gc[t]=gvec[512+t];
  __syncthreads();
  float u1=0,u2=0,u3=0,gw=0,bw=0;
  for(int c=0;c<256;++c){
    float wg=WgT[c*256+t];
    u1+=ga[c]*wg; u2+=gB[c]*wg; u3+=gc[c]*wg; gw+=wg;
    bw+=ldin(mb_,c,f)*ldin(mW,(size_t)t*256+c,f);
  }
  Uvec[t]=u1; Uvec[256+t]=u2; Uvec[512+t]=u3; Uvec[768+t]=gw;
  Uvec[1024+t]=bw+ldin(mbias,t,f);
  float a=ga[t], b=gB[t], cc=gc[t];
  float s0=a*a,s1=b*b,s2=cc*cc,s3=a*b; breduce4(s0,s1,s2,s3,red);
  float s4=a*cc,s5=b*cc,s6=a,s7=b;     breduce4(s4,s5,s6,s7,red);
  float s8=cc,z1=0,z2=0,z3=0;          breduce4(s8,z1,z2,z3,red);
  if(t==0){
    Qs[0]=s0; Qs[1]=s1; Qs[2]=s2; Qs[3]=s3; Qs[4]=s4; Qs[5]=s5;
    Qs[6]=s6*(1.f/256.f); Qs[7]=s7*(1.f/256.f); Qs[8]=s8*(1.f/256.f);
  }
}

// ---- fg_pos ----
__global__ void fgpos_kernel(const int* flag, const void* mask, float* fg, void* out)
{
  __shared__ float red[16];
  int k=blockIdx.x, t=threadIdx.x, f=*flag;
  float sx=0,sy=0,sm=0;
  for(int s=0;s<16;++s){
    int p=t+s*256;
    float m=ldin(mask,(size_t)k*N_+p,f);
    int i=p>>6, j=p&63;
    float x=(2*j+1)*(1.0f/64.0f)-1.0f;
    float y=(2*i+1)*(1.0f/64.0f)-1.0f;
    sx+=x*m; sy+=y*m; sm+=m;
  }
  float d=0;
  breduce4(sx,sy,sm,d,red);
  if(t==0){
    float inv=1.0f/(sm+1e-5f);
    float fx=sx*inv, fy=sy*inv;
    fg[k*2]=fx; fg[k*2+1]=fy;
    for(int b=0;b<B_;++b){
      stout(out, 5120+(b*K_+k)*2+0, fx, f);
      stout(out, 5120+(b*K_+k)*2+1, fy, f);
    }
  }
}

// ---- base: LN(feat) -> kb/vb -> per-row scalars + Pk/Pv GEMMs ----
// 16 rows/block; wave w owns rows 4w..4w+3; kb aliases fn's LDS (wave-private rows).
__global__ void __launch_bounds__(256) base_kernel(const int* flag, const void* feat, const void* ng, const void* nb,
    const float* WkT, const float* WvT, const float* WgT, const float* gvec,
    float* scal, float* Pk, float* Pv)
{
  __shared__ float A[16][256];    // fn, then kb (aliased)
  __shared__ float Vb[16][256];   // vb; Vb[0][0..15] doubles as LN red buffer
  int t=threadIdx.x, f=*flag;
  int row0=blockIdx.x*16;
  float g=ldin(ng,t,f), bb=ldin(nb,t,f);
  float* red=&Vb[0][0];
  for(int r=0;r<16;++r){
    float x=ldin(feat,(size_t)(row0+r)*256+t,f);
    float s=x,s2=x*x,z0=0,z1=0; breduce4(s,s2,z0,z1,red);
    float m=s*(1.f/256.f), var=s2*(1.f/256.f)-m*m;
    A[r][t]=(x-m)*rsqrtf(var+EPS_)*g+bb;
  }
  __syncthreads();
  int w=t>>6, l=t&63, d0=l*4;
  float ak[4][4]={{0}}, av[4][4]={{0}};
  for(int c=0;c<256;++c){
    float4 wk=*(const float4*)(WkT+c*256+d0);
    float4 wv=*(const float4*)(WvT+c*256+d0);
    #pragma unroll
    for(int r=0;r<4;++r){
      float f0=A[4*w+r][c];
      ak[r][0]+=f0*wk.x; ak[r][1]+=f0*wk.y; ak[r][2]+=f0*wk.z; ak[r][3]+=f0*wk.w;
      av[r][0]+=f0*wv.x; av[r][1]+=f0*wv.y; av[r][2]+=f0*wv.z; av[r][3]+=f0*wv.w;
    }
  }
  __syncthreads();   // all LN reads & pass1 reads complete before overwrite
  #pragma unroll
  for(int r=0;r<4;++r){
    *(float4*)&A[4*w+r][d0] =make_float4(ak[r][0],ak[r][1],ak[r][2],ak[r][3]);
    *(float4*)&Vb[4*w+r][d0]=make_float4(av[r][0],av[r][1],av[r][2],av[r][3]);
  }
  __syncthreads();
  // scalar sums: wave w handles its own rows, lanes sum stride-64 columns (no barriers)
  float gA0=gvec[l], gA1=gvec[l+64], gA2=gvec[l+128], gA3=gvec[l+192];
  float gB0=gvec[256+l], gB1=gvec[256+l+64], gB2=gvec[256+l+128], gB3=gvec[256+l+192];
  float gC0=gvec[512+l], gC1=gvec[512+l+64], gC2=gvec[512+l+128], gC3=gvec[512+l+192];
  for(int r4=0;r4<4;++r4){
    int r=4*w+r4;
    float k0=A[r][l], k1=A[r][l+64], k2=A[r][l+128], k3=A[r][l+192];
    float x0=Vb[r][l], x1=Vb[r][l+64], x2=Vb[r][l+128], x3=Vb[r][l+192];
    float v0=k0+k1+k2+k3;
    float v1=k0*k0+k1*k1+k2*k2+k3*k3;
    float v2=k0*gA0+k1*gA1+k2*gA2+k3*gA3;
    float v3=k0*gB0+k1*gB1+k2*gB2+k3*gB3;
    float v4=k0*gC0+k1*gC1+k2*gC2+k3*gC3;
    float v5=x0+x1+x2+x3;
    float v6=x0*x0+x1*x1+x2*x2+x3*x3;
    float v7=x0*gA0+x1*gA1+x2*gA2+x3*gA3;
    float v8=x0*gB0+x1*gB1+x2*gB2+x3*gB3;
    float v9=x0*gC0+x1*gC1+x2*gC2+x3*gC3;
    #pragma unroll
    for(int o=32;o>0;o>>=1){
      v0+=__shfl_down(v0,o,64); v1+=__shfl_down(v1,o,64); v2+=__shfl_down(v2,o,64);
      v3+=__shfl_down(v3,o,64); v4+=__shfl_down(v4,o,64); v5+=__shfl_down(v5,o,64);
      v6+=__shfl_down(v6,o,64); v7+=__shfl_down(v7,o,64); v8+=__shfl_down(v8,o,64);
      v9+=__shfl_down(v9,o,64);
    }
    if(l==0){
      float* sc=scal+(size_t)(row0+r)*10;
      sc[0]=v0; sc[1]=v1; sc[2]=v2; sc[3]=v3; sc[4]=v4;
      sc[5]=v5; sc[6]=v6; sc[7]=v7; sc[8]=v8; sc[9]=v9;
    }
  }
  // pass2: Pk/Pv = kb/vb @ WgT
  float pk[4][4]={{0}}, pv[4][4]={{0}};
  for(int c=0;c<256;++c){
    float4 wg=*(const float4*)(WgT+c*256+d0);
    #pragma unroll
    for(int r=0;r<4;++r){
      float kk0=A[4*w+r][c], vv0=Vb[4*w+r][c];
      pk[r][0]+=kk0*wg.x; pk[r][1]+=kk0*wg.y; pk[r][2]+=kk0*wg.z; pk[r][3]+=kk0*wg.w;
      pv[r][0]+=vv0*wg.x; pv[r][1]+=vv0*wg.y; pv[r][2]+=vv0*wg.z; pv[r][3]+=vv0*wg.w;
    }
  }
  #pragma unroll
  for(int r=0;r<4;++r){
    *(float4*)(Pk+(size_t)(row0+4*w+r)*256+d0)=make_float4(pk[r][0],pk[r][1],pk[r][2],pk[r][3]);
    *(float4*)(Pv+(size_t)(row0+4*w+r)*256+d0)=make_float4(pv[r][0],pv[r][1],pv[r][2],pv[r][3]);
  }
}

// ---- q projection (iter 0 only; later iters fused into gru tail) ----
__global__ void q_kernel(const int* flag, const float* slot, const void* qg, const void* qb_,
                         const float* WqT, const float* Uvec, float* qbuf, float* qsc)
{
  __shared__ float Lq[256]; __shared__ float qsh[256]; __shared__ float red[16];
  int bk=blockIdx.x, t=threadIdx.x, f=*flag;
  float x=slot[bk*256+t];
  float s=x,s2=x*x,z0=0,z1=0; breduce4(s,s2,z0,z1,red);
  float m=s*(1.f/256.f), v=s2*(1.f/256.f)-m*m;
  Lq[t]=(x-m)*rsqrtf(v+EPS_)*ldin(qg,t,f)+ldin(qb_,t,f);
  __syncthreads();
  float acc=0;
  for(int c=0;c<256;++c) acc+=Lq[c]*WqT[c*256+t];
  qbuf[bk*256+t]=acc; qsh[t]=acc;
  __syncthreads();
  float q=qsh[t];
  float s0=q*Uvec[t], s1=q*Uvec[256+t], s2b=q*Uvec[512+t], s3=q*Uvec[768+t];
  breduce4(s0,s1,s2b,s3,red);
  float s4=q*Uvec[1024+t], z2=0,z3=0,z4=0;
  breduce4(s4,z2,z3,z4,red);
  if(t==0){ qsc[bk*8+0]=s0; qsc[bk*8+1]=s1; qsc[bk*8+2]=s2b; qsc[bk*8+3]=s3; qsc[bk*8+4]=s4; }
}

// ---- logits: coalesced wave-per-row, all 5 slots per Pk read; invK/mK inline ----
__global__ void __launch_bounds__(256) logits_kernel(const int* flag, const float* qbuf, const float* Pk,
    const float* scal, const float* Qs, const float* qsc, const float* fg, const void* mask, float* logits)
{
  __shared__ float q5[5][256];
  __shared__ float qs5[5][8];
  __shared__ float fgs[10];
  __shared__ float Qss[9];
  int t=threadIdx.x, f=*flag;
  int b=blockIdx.x>>6, chunk=blockIdx.x&63;
  int n0=chunk*64;
  #pragma unroll
  for(int k=0;k<5;++k) q5[k][t]=qbuf[(size_t)(b*5+k)*256+t];
  if(t<40) qs5[t>>3][t&7]=qsc[(size_t)(b*5+(t>>3))*8+(t&7)];
  if(t<10) fgs[t]=fg[t];
  if(t<9)  Qss[t]=Qs[t];
  __syncthreads();
  int w=t>>6, l=t&63;
  for(int rr=0; rr<16; ++rr){
    int n=n0 + w*16 + rr;
    size_t row=(size_t)b*N_+n;
    float4 p=*(const float4*)(Pk+row*256+l*4);
    float dk0,dk1,dk2,dk3,dk4;
    { const float* qq=&q5[0][l*4]; dk0=p.x*qq[0]+p.y*qq[1]+p.z*qq[2]+p.w*qq[3]; }
    { const float* qq=&q5[1][l*4]; dk1=p.x*qq[0]+p.y*qq[1]+p.z*qq[2]+p.w*qq[3]; }
    { const float* qq=&q5[2][l*4]; dk2=p.x*qq[0]+p.y*qq[1]+p.z*qq[2]+p.w*qq[3]; }
    { const float* qq=&q5[3][l*4]; dk3=p.x*qq[0]+p.y*qq[1]+p.z*qq[2]+p.w*qq[3]; }
    { const float* qq=&q5[4][l*4]; dk4=p.x*qq[0]+p.y*qq[1]+p.z*qq[2]+p.w*qq[3]; }
    #pragma unroll
    for(int o=1;o<64;o<<=1){
      dk0+=__shfl_xor(dk0,o,64); dk1+=__shfl_xor(dk1,o,64); dk2+=__shfl_xor(dk2,o,64);
      dk3+=__shfl_xor(dk3,o,64); dk4+=__shfl_xor(dk4,o,64);
    }
    if(l<5){
      int k=l;
      float dot=dk0;
      if(k==1)dot=dk1; else if(k==2)dot=dk2; else if(k==3)dot=dk3; else if(k==4)dot=dk4;
      const float* sc=scal+row*10;
      float rx=(2*(n&63)+1)*(1.f/64.f)-1.f-fgs[2*k];
      float ry=(2*(n>>6)+1)*(1.f/64.f)-1.f-fgs[2*k+1];
      float qge=rx*rx*Qss[0]+ry*ry*Qss[1]+Qss[2]+2.f*(rx*ry*Qss[3]+rx*Qss[4]+ry*Qss[5]);
      float mk=sc[0]*(1.f/256.f)+rx*Qss[6]+ry*Qss[7]+Qss[8];
      float sxk=sc[1]+2.f*(rx*sc[2]+ry*sc[3]+sc[4])+qge;
      float vk=sxk*(1.f/256.f)-mk*mk;
      float invK=rsqrtf(vk+EPS_);
      float lg=invK*(dot+rx*qs5[k][0]+ry*qs5[k][1]+qs5[k][2]-mk*qs5[k][3])+qs5[k][4];
      float mval=ldin(mask,(size_t)k*N_+n,f);
      logits[((size_t)(b*5+k))*N_+n]=(mval==0.f)? -1e9f : lg*0.0625f;
    }
  }
}

// ---- softmax + w=attn*invV + scalar sums (invV/mV inline) ----
__global__ void wsum_kernel(const float* logits, const float* scal, const float* Qs, const float* fg,
                            float* attn, float* wbuf, float* ssc)
{
  __shared__ float red[16];
  int bk=blockIdx.x, t=threadIdx.x;
  int k=bk%K_, b=bk/K_;
  float l[16]; float mx=-1e30f;
  for(int s=0;s<16;++s){ l[s]=logits[(size_t)bk*N_+t+s*256]; mx=fmaxf(mx,l[s]); }
  mx=breduce_max(mx,red);
  float sum=0;
  for(int s=0;s<16;++s){ l[s]=expf(l[s]-mx); sum+=l[s]; }
  sum=breduce_sum(sum,red);
  float inv=1.0f/sum;
  float fgx=fg[2*k], fgy=fg[2*k+1];
  float QA=Qs[0],QB=Qs[1],QC=Qs[2],QAB=Qs[3],QAC=Qs[4],QBC=Qs[5],mA=Qs[6],mB=Qs[7],mC=Qs[8];
  float sw=0,swx=0,swy=0,swm=0;
  for(int s=0;s<16;++s){
    int n=t+s*256;
    float a=l[s]*inv;
    attn[(size_t)bk*N_+n]=a;
    const float* sc=scal+(size_t)(b*N_+n)*10;
    float rx=(2*(n&63)+1)*(1.f/64.f)-1.f-fgx;
    float ry=(2*(n>>6)+1)*(1.f/64.f)-1.f-fgy;
    float qge=rx*rx*QA+ry*ry*QB+QC+2.f*(rx*ry*QAB+rx*QAC+ry*QBC);
    float mv=sc[5]*(1.f/256.f)+rx*mA+ry*mB+mC;
    float sxv=sc[6]+2.f*(rx*sc[7]+ry*sc[8]+sc[9])+qge;
    float vv_=sxv*(1.f/256.f)-mv*mv;
    float iv=rsqrtf(vv_+EPS_);
    float wgt=a*iv;
    wbuf[(size_t)bk*N_+n]=wgt;
    sw+=wgt; swx+=wgt*rx; swy+=wgt*ry; swm+=wgt*mv;
  }
  breduce4(swx,swy,sw,swm,red);
  if(t==0){ ssc[bk*4+0]=swx; ssc[bk*4+1]=swy; ssc[bk*4+2]=sw; ssc[bk*4+3]=swm; }
}

// ---- upd partials: all 5 k per Pv read; partials to gmem (no atomics) ----
__global__ void __launch_bounds__(256) upd_kernel(const float* wbuf, const float* Pv, float* updpart)
{
  __shared__ float part[4][5][256];
  int t=threadIdx.x, w=t>>6, l=t&63;
  int b=blockIdx.x>>6, chunk=blockIdx.x&63;
  int n0=chunk*64 + w*16;
  float acc[5][4]={{0}};
  for(int rr=0;rr<16;++rr){
    int n=n0+rr;
    size_t row=(size_t)b*N_+n;
    float4 p=*(const float4*)(Pv+row*256+l*4);
    #pragma unroll
    for(int k=0;k<5;++k){
      float wg=wbuf[((size_t)(b*5+k))*N_+n];
      acc[k][0]+=wg*p.x; acc[k][1]+=wg*p.y; acc[k][2]+=wg*p.z; acc[k][3]+=wg*p.w;
    }
  }
  #pragma unroll
  for(int k=0;k<5;++k)
    *(float4*)&part[w][k][l*4]=make_float4(acc[k][0],acc[k][1],acc[k][2],acc[k][3]);
  __syncthreads();
  #pragma unroll
  for(int k=0;k<5;++k){
    float v=part[0][k][t]+part[1][k][t]+part[2][k][t]+part[3][k][t];
    updpart[((size_t)blockIdx.x*5+k)*256+t]=v;
  }
}

// ---- GRU + residual MLP slot update + NEXT-ITER q projection (fused) ----
__global__ void __launch_bounds__(256) gru_kernel(const int* flag, float* slot, const float* updpart,
    const float* Uvec, const float* ssc,
    const float* WihT, const float* WhhT, const void* bih, const void* bhh,
    const void* rg, const void* rb_, const float* WrT, const void* rbias,
    const void* qg, const void* qb_, const float* WqT, float* qbuf, float* qsc)
{
  __shared__ float u[256], h[256], Ln[256], red[16];
  int bk=blockIdx.x, t=threadIdx.x, f=*flag;
  int k=bk%K_, b=bk/K_;
  float uacc=0;
  for(int ch=0;ch<64;++ch) uacc+=updpart[(((size_t)(b*64+ch))*5+k)*256+t];
  float c1=ssc[bk*4+0], c2=ssc[bk*4+1], c3=ssc[bk*4+2], c4=ssc[bk*4+3];
  u[t]=uacc+c1*Uvec[t]+c2*Uvec[256+t]+c3*Uvec[512+t]-c4*Uvec[768+t]+Uvec[1024+t];
  h[t]=slot[bk*256+t];
  __syncthreads();
  float gi0=ldin(bih,t,f), gi1=ldin(bih,256+t,f), gi2=ldin(bih,512+t,f);
  float gh0=ldin(bhh,t,f), gh1=ldin(bhh,256+t,f), gh2=ldin(bhh,512+t,f);
  #pragma unroll 4
  for(int c=0;c<256;++c){
    float uc=u[c], hc=h[c];
    const float* wi=WihT+c*768+t;
    const float* wh=WhhT+c*768+t;
    gi0+=uc*wi[0]; gi1+=uc*wi[256]; gi2+=uc*wi[512];
    gh0+=hc*wh[0]; gh1+=hc*wh[256]; gh2+=hc*wh[512];
  }
  float r=1.f/(1.f+expf(-(gi0+gh0)));
  float z=1.f/(1.f+expf(-(gi1+gh1)));
  float nn=tanhf(gi2+r*gh2);
  float hn=(1.f-z)*nn+z*h[t];
  float s=hn, sq=hn*hn, z0=0, z1=0;
  breduce4(s,sq,z0,z1,red);
  float m=s*(1.f/256.f), var=sq*(1.f/256.f)-m*m;
  Ln[t]=(hn-m)*rsqrtf(var+EPS_)*ldin(rg,t,f)+ldin(rb_,t,f);
  __syncthreads();
  float acc=ldin(rbias,t,f)+h[t];
  for(int c=0;c<256;++c) acc+=Ln[c]*WrT[c*256+t];
  slot[bk*256+t]=acc;
  // ---- fused next-iter q projection ----
  __syncthreads();           // done with u/Ln contents
  float s0=acc, s1=acc*acc, z2=0, z3=0;
  breduce4(s0,s1,z2,z3,red);
  float mq=s0*(1.f/256.f), vq=s1*(1.f/256.f)-mq*mq;
  u[t]=(acc-mq)*rsqrtf(vq+EPS_)*ldin(qg,t,f)+ldin(qb_,t,f);   // reuse u as Lq
  __syncthreads();
  float qv=0;
  for(int c=0;c<256;++c) qv+=u[c]*WqT[c*256+t];
  qbuf[bk*256+t]=qv; h[t]=qv;                                  // reuse h as qsh
  __syncthreads();
  float q=h[t];
  float a0=q*Uvec[t], a1=q*Uvec[256+t], a2=q*Uvec[512+t], a3=q*Uvec[768+t];
  breduce4(a0,a1,a2,a3,red);
  float a4=q*Uvec[1024+t], z4=0,z5=0,z6=0;
  breduce4(a4,z4,z5,z6,red);
  if(t==0){ qsc[bk*8+0]=a0; qsc[bk*8+1]=a1; qsc[bk*8+2]=a2; qsc[bk*8+3]=a3; qsc[bk*8+4]=a4; }
}

// ---- outputs ----
__global__ void slotout_kernel(const int* flag, const float* slot, void* out)
{
  int e=blockIdx.x*256+threadIdx.x;
  stout(out, e, slot[e], *flag);
}
__global__ void vis_kernel(const int* flag, const float* attn, void* out)
{
  __shared__ float red[16];
  int bk=blockIdx.x, t=threadIdx.x, f=*flag;
  float a[16]; float mn=1e30f, mx=-1e30f;
  for(int s=0;s<16;++s){ a[s]=attn[(size_t)bk*N_+t+s*256]; mn=fminf(mn,a[s]); mx=fmaxf(mx,a[s]); }
  breduce_minmax(mn,mx,red);
  float inv=1.0f/(mx-mn+1e-5f);
  for(int s=0;s<16;++s) stout(out, 5160+(size_t)bk*N_+t+s*256, (a[s]-mn)*inv, f);
}

extern "C" void kernel_launch(void* const* d_in, const int* in_sizes, int n_in,
                              void* d_out, int out_size, void* d_ws, size_t ws_size,
                              hipStream_t stream)
{
  const void* feat =d_in[0];  const void* mask =d_in[1];  const void* noise=d_in[2];
  const void* mu   =d_in[3];  const void* lsig =d_in[4];  const void* ng   =d_in[5];
  const void* nb   =d_in[6];  const void* gW   =d_in[7];  const void* gb_  =d_in[8];
  const void* kW   =d_in[9];  const void* vW   =d_in[10]; const void* mg   =d_in[11];
  const void* mb_  =d_in[12]; const void* mW   =d_in[13]; const void* mbias=d_in[14];
  const void* qg   =d_in[15]; const void* qb_  =d_in[16]; const void* qW   =d_in[17];
  const void* Wih  =d_in[18]; const void* Whh  =d_in[19]; const void* bih  =d_in[20];
  const void* bhh  =d_in[21]; const void* rg   =d_in[22]; const void* rb_  =d_in[23];
  const void* rW   =d_in[24]; const void* rbias=d_in[25];

  char* p=(char*)d_ws;
  auto alloc=[&](size_t bytes)->char*{ char* r=p; p+=(bytes+255)&~(size_t)255; return r; };
  int*   flag   =(int*)  alloc(256);
  float* fg     =(float*)alloc(64);
  float* slot   =(float*)alloc(5120*4);
  float* qbuf   =(float*)alloc(5120*4);
  float* qsc    =(float*)alloc(160*4);
  float* ssc    =(float*)alloc(80*4);
  float* logits =(float*)alloc((size_t)81920*4);
  float* attn   =(float*)alloc((size_t)81920*4);
  float* wbuf   =(float*)alloc((size_t)81920*4);
  float* updpart=(float*)alloc((size_t)256*5*256*4);
  float* WkT    =(float*)alloc((size_t)65536*4);
  float* WvT    =(float*)alloc((size_t)65536*4);
  float* WgT    =(float*)alloc((size_t)65536*4);
  float* WqT    =(float*)alloc((size_t)65536*4);
  float* WrT    =(float*)alloc((size_t)65536*4);
  float* WihT   =(float*)alloc((size_t)196608*4);
  float* WhhT   =(float*)alloc((size_t)196608*4);
  float* gvec   =(float*)alloc(768*4);
  float* Uvec   =(float*)alloc(1280*4);
  float* Qs     =(float*)alloc(64);
  float* scal   =(float*)alloc((size_t)163840*4);
  float* Pk     =(float*)alloc((size_t)16384*256*4);
  float* Pv     =(float*)alloc((size_t)16384*256*4);

  probe_kernel<<<1,256,0,stream>>>(feat, flag);
  prep1_kernel<<<2839,256,0,stream>>>(flag,kW,vW,mW,qW,rW,Wih,Whh,mu,lsig,noise,gW,gb_,mg,
                                      WkT,WvT,WgT,WqT,WrT,WihT,WhhT,slot,gvec);
  uq_kernel<<<1,256,0,stream>>>(flag,WgT,mW,mb_,mbias,gvec,Uvec,Qs);
  fgpos_kernel<<<K_,256,0,stream>>>(flag,mask,fg,d_out);
  base_kernel<<<(B_*N_)/16,256,0,stream>>>(flag,feat,ng,nb,WkT,WvT,WgT,gvec,scal,Pk,Pv);
  q_kernel<<<B_*K_,256,0,stream>>>(flag,slot,qg,qb_,WqT,Uvec,qbuf,qsc);
  for(int it=0; it<IT_; ++it){
    logits_kernel<<<B_*64,256,0,stream>>>(flag,qbuf,Pk,scal,Qs,qsc,fg,mask,logits);
    wsum_kernel<<<B_*K_,256,0,stream>>>(logits,scal,Qs,fg,attn,wbuf,ssc);
    upd_kernel<<<B_*64,256,0,stream>>>(wbuf,Pv,updpart);
    gru_kernel<<<B_*K_,256,0,stream>>>(flag,slot,updpart,Uvec,ssc,WihT,WhhT,bih,bhh,
                                       rg,rb_,WrT,rbias,qg,qb_,WqT,qbuf,qsc);
  }
  slotout_kernel<<<B_*K_,256,0,stream>>>(flag,slot,d_out);
  vis_kernel<<<B_*K_,256,0,stream>>>(flag,attn,d_out);
}